// Round 1
// baseline (134.355 us; speedup 1.0000x reference)
//
#include <hip/hip_runtime.h>

#define H_IMG 384
#define W_IMG 640
#define NPAIR 4
#define NBATCH 8
#define NBOX 100
#define DHID 256

// ---------------------------------------------------------------------------
// Kernel 1: for each (pair, row): diff = |sum_c img[2p+1] - sum_c img[2p]|,
// then inclusive scan across the row, written as double into sat[p][h][w].
// One wave (64 lanes) per row; 10 chunks of 64 cols with shfl_up wave scan.
// ---------------------------------------------------------------------------
__global__ __launch_bounds__(64) void k_diff_rowscan(const float* __restrict__ images,
                                                     double* __restrict__ sat) {
    const int row = blockIdx.x;            // 0 .. NPAIR*H_IMG-1
    const int p = row / H_IMG;
    const int h = row - p * H_IMG;
    const int lane = threadIdx.x;          // 0..63

    const size_t chw = (size_t)H_IMG * W_IMG;            // channel stride
    // images[b][c][h][w] flat = ((b*3 + c)*H + h)*W + w
    const float* i0 = images + ((size_t)(2 * p)     * 3 * H_IMG + h) * W_IMG;
    const float* i1 = images + ((size_t)(2 * p + 1) * 3 * H_IMG + h) * W_IMG;
    double* srow = sat + ((size_t)p * H_IMG + h) * W_IMG;

    double carry = 0.0;
    #pragma unroll
    for (int k = 0; k < W_IMG / 64; ++k) {
        const int w = k * 64 + lane;
        // channel sums in fp32 (matches jnp images.sum(axis=1) order (c0+c1)+c2)
        float s0 = (i0[w] + i0[w + chw]) + i0[w + 2 * chw];
        float s1 = (i1[w] + i1[w + chw]) + i1[w + 2 * chw];
        double v = (double)fabsf(s1 - s0);
        // wave-64 inclusive scan
        #pragma unroll
        for (int off = 1; off < 64; off <<= 1) {
            double u = __shfl_up(v, off, 64);
            if (lane >= off) v += u;
        }
        v += carry;
        srow[w] = v;
        carry = __shfl(v, 63, 64);         // broadcast running total
    }
}

// ---------------------------------------------------------------------------
// Kernel 2: inclusive scan down each column (coalesced: consecutive threads
// own consecutive columns). sat becomes the full 2D summed-area table.
// ---------------------------------------------------------------------------
__global__ __launch_bounds__(256) void k_colscan(double* __restrict__ sat) {
    const int idx = blockIdx.x * blockDim.x + threadIdx.x;   // 0 .. NPAIR*W-1
    if (idx >= NPAIR * W_IMG) return;
    const int p = idx / W_IMG;
    const int c = idx - p * W_IMG;
    double* col = sat + (size_t)p * H_IMG * W_IMG + c;
    double run = 0.0;
    #pragma unroll 4
    for (int h = 0; h < H_IMG; ++h) {
        run += col[(size_t)h * W_IMG];
        col[(size_t)h * W_IMG] = run;
    }
}

// ---------------------------------------------------------------------------
// Kernel 3: one block per batch. Scores via SAT lookups, serial top-2
// (jax.lax.top_k tie-break: lower index first), gather hidden states,
// fused Linear (x @ W^T + b), write interleaved [:,0]/[:,1] output layout.
// ---------------------------------------------------------------------------
__global__ __launch_bounds__(256) void k_score_topk_fc(
        const double* __restrict__ sat,
        const float* __restrict__ pred_boxes,
        const float* __restrict__ lhs,
        const float* __restrict__ fc_w,
        const float* __restrict__ fc_b,
        float* __restrict__ out) {
    const int b = blockIdx.x;
    const int t = threadIdx.x;

    __shared__ float s_score[NBOX];
    __shared__ int   s_idx[2];
    __shared__ float s_h[2][DHID];

    const double* S = sat + (size_t)(b >> 1) * H_IMG * W_IMG;

    if (t < NBOX) {
        const float* pb = pred_boxes + ((size_t)b * NBOX + t) * 4;
        const float cx = pb[0], cy = pb[1], bw = pb[2], bh = pb[3];
        // cxcywh -> xyxy, scale by [W,H,W,H], truncate toward zero (.astype(int32))
        const int bb0 = (int)((cx - 0.5f * bw) * 640.0f);   // vs row index (H range)
        const int bb1 = (int)((cy - 0.5f * bh) * 384.0f);   // vs col index (W range)
        const int bb2 = (int)((cx + 0.5f * bw) * 640.0f);
        const int bb3 = (int)((cy + 0.5f * bh) * 384.0f);
        const int r0 = bb0 > 0 ? bb0 : 0;
        const int r2 = bb2 < H_IMG - 1 ? bb2 : H_IMG - 1;
        const int c0 = bb1 > 0 ? bb1 : 0;
        const int c2 = bb3 < W_IMG - 1 ? bb3 : W_IMG - 1;
        float sc = 0.0f;
        if (r0 <= r2 && c0 <= c2) {
            double sum = S[(size_t)r2 * W_IMG + c2];
            if (r0 > 0)           sum -= S[(size_t)(r0 - 1) * W_IMG + c2];
            if (c0 > 0)           sum -= S[(size_t)r2 * W_IMG + (c0 - 1)];
            if (r0 > 0 && c0 > 0) sum += S[(size_t)(r0 - 1) * W_IMG + (c0 - 1)];
            sc = (float)(sum / (double)(H_IMG * W_IMG));
        }
        s_score[t] = sc;
    }
    __syncthreads();

    if (t == 0) {
        float b0 = -1e30f, b1 = -1e30f;
        int i0 = 0, i1 = 0;
        for (int n = 0; n < NBOX; ++n) {
            const float s = s_score[n];
            if (s > b0)      { b1 = b0; i1 = i0; b0 = s; i0 = n; }
            else if (s > b1) { b1 = s; i1 = n; }
        }
        s_idx[0] = i0;
        s_idx[1] = i1;
    }
    __syncthreads();

    // stage the two selected hidden vectors
    s_h[0][t] = lhs[((size_t)b * NBOX + s_idx[0]) * DHID + t];
    s_h[1][t] = lhs[((size_t)b * NBOX + s_idx[1]) * DHID + t];
    __syncthreads();

    // Linear: out[o][j] = fc_b[j] + sum_d h[o][d] * fc_w[j][d]
    const float* wrow = fc_w + (size_t)t * DHID;
    float acc0 = fc_b[t];
    float acc1 = acc0;
    #pragma unroll 4
    for (int d = 0; d < DHID; ++d) {
        const float wv = wrow[d];
        acc0 = fmaf(s_h[0][d], wv, acc0);
        acc1 = fmaf(s_h[1][d], wv, acc1);
    }

    // h_i.reshape(B/2, 2, O, 256); out0 = [:,0] (even b), out1 = [:,1] (odd b)
    const size_t base = (size_t)(b & 1) * (NPAIR * 2 * DHID) + (size_t)(b >> 1) * (2 * DHID);
    out[base + t]        = acc0;   // o = 0 (best)
    out[base + DHID + t] = acc1;   // o = 1 (second)
}

extern "C" void kernel_launch(void* const* d_in, const int* in_sizes, int n_in,
                              void* d_out, int out_size, void* d_ws, size_t ws_size,
                              hipStream_t stream) {
    const float* images     = (const float*)d_in[0];
    // d_in[1] = logits: dead code in the reference (softmax result unused)
    const float* pred_boxes = (const float*)d_in[2];
    const float* lhs        = (const float*)d_in[3];
    const float* fc_w       = (const float*)d_in[4];
    const float* fc_b       = (const float*)d_in[5];
    float* out              = (float*)d_out;
    double* sat             = (double*)d_ws;   // 4*384*640*8 = 7.86 MB

    hipLaunchKernelGGL(k_diff_rowscan, dim3(NPAIR * H_IMG), dim3(64), 0, stream,
                       images, sat);
    hipLaunchKernelGGL(k_colscan, dim3((NPAIR * W_IMG + 255) / 256), dim3(256), 0, stream,
                       sat);
    hipLaunchKernelGGL(k_score_topk_fc, dim3(NBATCH), dim3(256), 0, stream,
                       sat, pred_boxes, lhs, fc_w, fc_b, out);
}

// Round 2
// 100.964 us; speedup vs baseline: 1.3307x; 1.3307x over previous
//
#include <hip/hip_runtime.h>

#define H_IMG 384
#define W_IMG 640
#define NPAIR 4
#define NBATCH 8
#define NBOX 100
#define DHID 256
#define ROWTILE 24
#define NTILES (H_IMG / ROWTILE)   // 16

// ---------------------------------------------------------------------------
// Kernel 1: for each (pair, row): diff = |sum_c img[2p+1] - sum_c img[2p]|,
// inclusive scan across the row (fp32), written to rowpref[p][h][w].
// 256-thread blocks = 4 waves, one row per wave.
// ---------------------------------------------------------------------------
__global__ __launch_bounds__(256) void k_diff_rowscan(const float* __restrict__ images,
                                                      float* __restrict__ sat) {
    const int row = blockIdx.x * 4 + (threadIdx.x >> 6);   // 0 .. NPAIR*H_IMG-1
    const int lane = threadIdx.x & 63;
    const int p = row / H_IMG;
    const int h = row - p * H_IMG;

    const size_t chw = (size_t)H_IMG * W_IMG;
    const float* i0 = images + ((size_t)(2 * p)     * 3 * H_IMG + h) * W_IMG;
    const float* i1 = images + ((size_t)(2 * p + 1) * 3 * H_IMG + h) * W_IMG;
    float* srow = sat + ((size_t)p * H_IMG + h) * W_IMG;

    float carry = 0.0f;
    #pragma unroll
    for (int k = 0; k < W_IMG / 64; ++k) {
        const int w = k * 64 + lane;
        float s0 = (i0[w] + i0[w + chw]) + i0[w + 2 * chw];
        float s1 = (i1[w] + i1[w + chw]) + i1[w + 2 * chw];
        float v = fabsf(s1 - s0);
        #pragma unroll
        for (int off = 1; off < 64; off <<= 1) {
            float u = __shfl_up(v, off, 64);
            if (lane >= off) v += u;
        }
        v += carry;
        srow[w] = v;
        carry = __shfl(v, 63, 64);
    }
}

// ---------------------------------------------------------------------------
// Kernel 2: local column scan within 24-row tiles (in place), emit tile totals.
// One wave per (pair, 64-col group, row tile): 4*10*16 = 640 waves.
// ---------------------------------------------------------------------------
__global__ __launch_bounds__(64) void k_colscan_local(float* __restrict__ sat,
                                                      float* __restrict__ totals) {
    const int bid = blockIdx.x;
    const int p  = bid / (10 * NTILES);
    const int r1 = bid - p * (10 * NTILES);
    const int t  = r1 / 10;
    const int cg = r1 - t * 10;
    const int c  = cg * 64 + (int)threadIdx.x;

    float* base = sat + ((size_t)p * H_IMG + t * ROWTILE) * W_IMG + c;
    float run = 0.0f;
    #pragma unroll
    for (int i = 0; i < ROWTILE; ++i) {
        run += base[(size_t)i * W_IMG];
        base[(size_t)i * W_IMG] = run;
    }
    totals[((size_t)p * NTILES + t) * W_IMG + c] = run;
}

// ---------------------------------------------------------------------------
// Kernel 3: one block per batch. Build exclusive tile-offset table in LDS,
// score all boxes via on-the-fly SAT lookups, serial top-2 (jax tie-break),
// gather hidden states, fused Linear, interleaved output write.
// ---------------------------------------------------------------------------
__global__ __launch_bounds__(256) void k_score_topk_fc(
        const float* __restrict__ sat,
        const float* __restrict__ totals,
        const float* __restrict__ pred_boxes,
        const float* __restrict__ lhs,
        const float* __restrict__ fc_w,
        const float* __restrict__ fc_b,
        float* __restrict__ out) {
    const int b = blockIdx.x;
    const int t = threadIdx.x;
    const int p = b >> 1;

    __shared__ float s_off[NTILES][W_IMG];   // 40 KB: exclusive column-tile offsets
    __shared__ float s_score[NBOX];
    __shared__ int   s_idx[2];
    __shared__ float s_h[2][DHID];

    // Phase A: exclusive prefix of tile totals per column
    for (int c = t; c < W_IMG; c += 256) {
        float run = 0.0f;
        #pragma unroll
        for (int tt = 0; tt < NTILES; ++tt) {
            s_off[tt][c] = run;
            run += totals[((size_t)p * NTILES + tt) * W_IMG + c];
        }
    }
    __syncthreads();

    const float* S = sat + (size_t)p * H_IMG * W_IMG;

    // Phase B: scores via SAT(r,c) = local[r][c] + s_off[r/24][c]
    if (t < NBOX) {
        const float* pb = pred_boxes + ((size_t)b * NBOX + t) * 4;
        const float cx = pb[0], cy = pb[1], bw = pb[2], bh = pb[3];
        const int bb0 = (int)((cx - 0.5f * bw) * 640.0f);   // vs row index
        const int bb1 = (int)((cy - 0.5f * bh) * 384.0f);   // vs col index
        const int bb2 = (int)((cx + 0.5f * bw) * 640.0f);
        const int bb3 = (int)((cy + 0.5f * bh) * 384.0f);
        const int r0 = bb0 > 0 ? bb0 : 0;
        const int r2 = bb2 < H_IMG - 1 ? bb2 : H_IMG - 1;
        const int c0 = bb1 > 0 ? bb1 : 0;
        const int c2 = bb3 < W_IMG - 1 ? bb3 : W_IMG - 1;
        float sc = 0.0f;
        if (r0 <= r2 && c0 <= c2) {
            float sum = S[(size_t)r2 * W_IMG + c2] + s_off[r2 / ROWTILE][c2];
            if (r0 > 0) sum -= S[(size_t)(r0 - 1) * W_IMG + c2] + s_off[(r0 - 1) / ROWTILE][c2];
            if (c0 > 0) sum -= S[(size_t)r2 * W_IMG + (c0 - 1)] + s_off[r2 / ROWTILE][c0 - 1];
            if (r0 > 0 && c0 > 0)
                sum += S[(size_t)(r0 - 1) * W_IMG + (c0 - 1)] + s_off[(r0 - 1) / ROWTILE][c0 - 1];
            sc = sum / (float)(H_IMG * W_IMG);
        }
        s_score[t] = sc;
    }
    __syncthreads();

    // Phase C: top-2, lower index wins ties (jax.lax.top_k)
    if (t == 0) {
        float b0 = -1e30f, b1 = -1e30f;
        int i0 = 0, i1 = 0;
        for (int n = 0; n < NBOX; ++n) {
            const float s = s_score[n];
            if (s > b0)      { b1 = b0; i1 = i0; b0 = s; i0 = n; }
            else if (s > b1) { b1 = s; i1 = n; }
        }
        s_idx[0] = i0;
        s_idx[1] = i1;
    }
    __syncthreads();

    // Phase D: gather + Linear
    s_h[0][t] = lhs[((size_t)b * NBOX + s_idx[0]) * DHID + t];
    s_h[1][t] = lhs[((size_t)b * NBOX + s_idx[1]) * DHID + t];
    __syncthreads();

    const float* wrow = fc_w + (size_t)t * DHID;
    float acc0 = fc_b[t];
    float acc1 = acc0;
    #pragma unroll 4
    for (int d = 0; d < DHID; ++d) {
        const float wv = wrow[d];
        acc0 = fmaf(s_h[0][d], wv, acc0);
        acc1 = fmaf(s_h[1][d], wv, acc1);
    }

    const size_t base = (size_t)(b & 1) * (NPAIR * 2 * DHID) + (size_t)(b >> 1) * (2 * DHID);
    out[base + t]        = acc0;
    out[base + DHID + t] = acc1;
}

extern "C" void kernel_launch(void* const* d_in, const int* in_sizes, int n_in,
                              void* d_out, int out_size, void* d_ws, size_t ws_size,
                              hipStream_t stream) {
    const float* images     = (const float*)d_in[0];
    const float* pred_boxes = (const float*)d_in[2];
    const float* lhs        = (const float*)d_in[3];
    const float* fc_w       = (const float*)d_in[4];
    const float* fc_b       = (const float*)d_in[5];
    float* out              = (float*)d_out;

    float* sat    = (float*)d_ws;                                   // 3.93 MB
    float* totals = sat + (size_t)NPAIR * H_IMG * W_IMG;            // 160 KB

    hipLaunchKernelGGL(k_diff_rowscan, dim3(NPAIR * H_IMG / 4), dim3(256), 0, stream,
                       images, sat);
    hipLaunchKernelGGL(k_colscan_local, dim3(NPAIR * 10 * NTILES), dim3(64), 0, stream,
                       sat, totals);
    hipLaunchKernelGGL(k_score_topk_fc, dim3(NBATCH), dim3(256), 0, stream,
                       sat, totals, pred_boxes, lhs, fc_w, fc_b, out);
}